// Round 1
// 1317.784 us; speedup vs baseline: 2.2447x; 2.2447x over previous
//
#include <hip/hip_runtime.h>

// Residual VQ: B=16, D=128, L=4096, K=8 codebooks x N=1024 entries.
// out0 (B,K,D,L) cumulative quantization sums, out1 (B,L,K) argmin indices.
//
// R2 changes vs R1 (405 us/step, VALU/LDS-bound fp32 outer product):
//  - Distance GEMM moved to the MFMA pipe via error-free fp16 Dekker split:
//    x = xh + xm, c = ch + cm (exact residuals, exact cross products in fp32).
//    Fused as one K_eff=512 GEMM (segments hh, hm, mh, mm) with
//    v_mfma_f32_16x16x32_f16. Dot error ~2^-22 * sum|x||c| -- below the fp32
//    summation-order noise the R1 kernel already had vs the JAX reference.
//  - prep_kernel pre-splits codebooks into fp16 h/m planes in workspace,
//    PRE-SWIZZLED (chunk c -> c ^ (row&15)) so global_load_lds can stage
//    linearly (linear LDS dest + swizzled source, swizzled frag reads).
//  - Block: 128 l x chunks of 128 n, 4 waves of 64n x 64l (4x4 MFMA tiles):
//    per k-step 8 ds_read_b128 feed 16 MFMAs (0.5 reads/MFMA).
//  - Same score form (||c||^2 - 2 dot), same strict-< + packed-key argmin
//    tie-break, same Phase-4 exact fp32 cumulative output.

#define BB 16
#define DD 128
#define LL 4096
#define KK 8
#define NN 1024

constexpr int TL  = 128;       // l-positions per block
constexpr int TN  = 128;       // n per chunk
constexpr int NCH = NN / TN;   // 8 chunks

typedef _Float16 half8 __attribute__((ext_vector_type(8)));
typedef float    f32x4 __attribute__((ext_vector_type(4)));

typedef __attribute__((address_space(3))) char lds_char;
typedef __attribute__((address_space(1))) const char gbl_char;

__device__ __forceinline__ void gload16(const void* g, void* l) {
    // stages 64 lanes x 16 B: per-lane global src, wave-uniform LDS base (+lane*16)
    __builtin_amdgcn_global_load_lds((gbl_char*)g, (lds_char*)l, 16, 0, 0);
}

// ---- prep: per codebook row: cnorm (fp32) + fp16 h/m split planes, pre-swizzled ----
// thread t handles row = t>>4, 8-elem group g = t&15.
// swizzle: logical 8-half group g stored at group (g ^ (row&15)).
__global__ void prep_kernel(const float* __restrict__ cb, float* __restrict__ cnorm,
                            _Float16* __restrict__ cbh, _Float16* __restrict__ cbm) {
    int t   = blockIdx.x * blockDim.x + threadIdx.x;   // 0 .. K*N*16-1
    int row = t >> 4;
    int g   = t & 15;
    const float* src = cb + (size_t)row * DD + g * 8;
    half8 h, m;
    float s = 0.f;
#pragma unroll
    for (int j = 0; j < 8; ++j) {
        float v = src[j];
        _Float16 hh = (_Float16)v;            // RN to fp16
        h[j] = hh;
        m[j] = (_Float16)(v - (float)hh);     // exact residual, RN to fp16
        s += v * v;
    }
    size_t pos = (size_t)row * DD + ((g ^ (row & 15)) * 8);
    *(half8*)(cbh + pos) = h;
    *(half8*)(cbm + pos) = m;
#pragma unroll
    for (int off = 1; off < 16; off <<= 1) s += __shfl_xor(s, off);
    if (g == 0) cnorm[row] = s;
}

__global__ __launch_bounds__(256, 1) void rvq_step(
    const float*    __restrict__ x,
    const float*    __restrict__ cbk,     // fp32 codebook k (N*D), for phase 4
    const _Float16* __restrict__ cbhk,    // pre-swizzled fp16 hi plane (N*D)
    const _Float16* __restrict__ cbmk,    // pre-swizzled fp16 mid plane (N*D)
    const float*    __restrict__ cnormk,  // N
    float* __restrict__ out0,             // B*K*D*L
    float* __restrict__ out1,             // B*L*K (float-encoded indices)
    int k)
{
    // 134 KB LDS -> 1 block/CU (intentional)
    __shared__ __align__(16) _Float16 xsh[TL * DD];   // 32 KB  x hi plane [l][d], swizzled
    __shared__ __align__(16) _Float16 xsm[TL * DD];   // 32 KB  x mid plane
    __shared__ __align__(16) _Float16 csh[TN * DD];   // 32 KB  cb hi chunk [n][d], swizzled
    __shared__ __align__(16) _Float16 csm[TN * DD];   // 32 KB  cb mid chunk
    __shared__ __align__(16) float cnl[TN];           // 512 B
    __shared__ unsigned long long red[2][TL];         // 2 KB
    __shared__ int idx_final[TL];                     // 512 B

    const int tid  = threadIdx.x;
    const int bidx = blockIdx.x;
    const int b    = bidx >> 5;             // LL/TL = 32 tiles per batch
    const int l0   = (bidx & 31) * TL;

    const float* prev = (k > 0) ? (out0 + ((size_t)b * KK + (k - 1)) * DD * LL) : nullptr;
    float* cur = out0 + ((size_t)b * KK + k) * DD * LL;

    const int lane = tid & 63;
    const int r15  = lane & 15;
    const int kg   = lane >> 4;     // 0..3 (k-group within MFMA)
    const int wid  = tid >> 6;      // 0..3
    const int wn   = wid & 1;       // n-half of chunk (64 rows)
    const int wl   = wid >> 1;      // l-half of tile  (64 rows)

    // ---- Phase 1: residual tile -> fp16 split planes in LDS (swizzled) ----
    {
        const int ll = tid & 127;
        const int dh = tid >> 7;    // 0..1: which 4-of-8 half of each d-group
        const int sw = ll & 15;
#pragma unroll
        for (int g = 0; g < 16; ++g) {
            union { _Float16 f[4]; unsigned long long u; } ph, pm;
#pragma unroll
            for (int j = 0; j < 4; ++j) {
                int d = g * 8 + dh * 4 + j;
                float v = x[((size_t)b * DD + d) * LL + l0 + ll];
                if (k > 0) v -= prev[(size_t)d * LL + l0 + ll];
                _Float16 hh = (_Float16)v;
                ph.f[j] = hh;
                pm.f[j] = (_Float16)(v - (float)hh);
            }
            int off = ll * 256 + ((g ^ sw) << 4) + dh * 8;   // bytes
            *(unsigned long long*)((char*)xsh + off) = ph.u;
            *(unsigned long long*)((char*)xsm + off) = pm.u;
        }
    }

    // per-lane fragment address constants.
    // A (codebook, M-dim): row = wn*64 + mi*16 + r15 ; B (x, N-dim): row = wl*64 + ni*16 + r15.
    // row&15 == r15 for all tiles, so the read-side XOR is uniformly r15.
    const int baseA = (wn * 64 + r15) * 256;
    const int baseB = (wl * 64 + r15) * 256;
    int offT[4];
#pragma unroll
    for (int t = 0; t < 4; ++t) offT[t] = (((t * 4 + kg) ^ r15) << 4);

    float minv[4];
    int   minn[4];
#pragma unroll
    for (int i = 0; i < 4; ++i) { minv[i] = 3.4e38f; minn[i] = 0; }

    const f32x4 zero4 = {0.f, 0.f, 0.f, 0.f};

    for (int c = 0; c < NCH; ++c) {
        const int n0c = c * TN;
        if (c) __syncthreads();   // previous chunk's compute done before restage

        // ---- stage cb chunk: pre-swizzled global -> linear LDS via global_load_lds ----
        {
            const int rowb = wid * 32;   // wave's 32 rows of the chunk
            const char* gh = (const char*)(cbhk + (size_t)(n0c + rowb) * DD) + lane * 16;
            const char* gm = (const char*)(cbmk + (size_t)(n0c + rowb) * DD) + lane * 16;
            char* lh = (char*)csh + rowb * 256;
            char* lm = (char*)csm + rowb * 256;
#pragma unroll
            for (int i = 0; i < 8; ++i) {          // 4 rows (1 KB) per instr
                gload16(gh + i * 1024, lh + i * 1024);
                gload16(gm + i * 1024, lm + i * 1024);
            }
            if (tid < TN) cnl[tid] = cnormk[n0c + tid];
        }
        asm volatile("s_waitcnt vmcnt(0)" ::: "memory");
        __syncthreads();

        f32x4 acc[4][4];
#pragma unroll
        for (int mi = 0; mi < 4; ++mi)
#pragma unroll
            for (int ni = 0; ni < 4; ++ni) acc[mi][ni] = zero4;

        // ---- fused split-GEMM: segments (xh,ch),(xh,cm),(xm,ch),(xm,cm), K=512 total ----
#pragma unroll
        for (int seg = 0; seg < 4; ++seg) {
            const char* cp = (const char*)((seg & 1) ? csm : csh);
            const char* xp = (const char*)((seg & 2) ? xsm : xsh);
#pragma unroll
            for (int t = 0; t < 4; ++t) {          // 4 k-steps of 32 per segment
                half8 av[4], bv[4];
#pragma unroll
                for (int mi = 0; mi < 4; ++mi)
                    av[mi] = *(const half8*)(cp + baseA + mi * 4096 + offT[t]);
#pragma unroll
                for (int ni = 0; ni < 4; ++ni)
                    bv[ni] = *(const half8*)(xp + baseB + ni * 4096 + offT[t]);
#pragma unroll
                for (int mi = 0; mi < 4; ++mi)
#pragma unroll
                    for (int ni = 0; ni < 4; ++ni)
                        acc[mi][ni] = __builtin_amdgcn_mfma_f32_16x16x32_f16(
                            av[mi], bv[ni], acc[mi][ni], 0, 0, 0);
            }
        }

        // ---- scores + running per-lane argmin ----
        // C/D layout: col = lane&15 (l), row = kg*4 + j (n within 16-tile)
        f32x4 cnv[4];
#pragma unroll
        for (int mi = 0; mi < 4; ++mi)
            cnv[mi] = *(const f32x4*)(cnl + wn * 64 + mi * 16 + kg * 4);
#pragma unroll
        for (int ni = 0; ni < 4; ++ni) {
#pragma unroll
            for (int mi = 0; mi < 4; ++mi) {
#pragma unroll
                for (int j = 0; j < 4; ++j) {
                    float sc = cnv[mi][j] - 2.f * acc[mi][ni][j];
                    // strict < + ascending per-lane visit order => earliest-n tie-break
                    if (sc < minv[ni]) {
                        minv[ni] = sc;
                        minn[ni] = n0c + wn * 64 + mi * 16 + kg * 4 + j;
                    }
                }
            }
        }
    }

    // ---- cross-lane (kg) + cross-wave (wn) argmin via packed keys ----
    {
        unsigned long long key[4];
#pragma unroll
        for (int ni = 0; ni < 4; ++ni) {
            unsigned u = __float_as_uint(minv[ni]);
            u = (u & 0x80000000u) ? ~u : (u | 0x80000000u);   // monotone map
            key[ni] = ((unsigned long long)u << 32) | (unsigned)minn[ni];
        }
#pragma unroll
        for (int off = 16; off < 64; off <<= 1) {
#pragma unroll
            for (int ni = 0; ni < 4; ++ni) {
                unsigned long long o = __shfl_xor(key[ni], off);
                if (o < key[ni]) key[ni] = o;
            }
        }
        if (kg == 0) {
#pragma unroll
            for (int ni = 0; ni < 4; ++ni)
                red[wn][wl * 64 + ni * 16 + r15] = key[ni];
        }
    }
    __syncthreads();
    if (tid < TL) {
        unsigned long long k0 = red[0][tid], k1 = red[1][tid];
        if (k1 < k0) k0 = k1;
        int n = (int)(k0 & 0xFFFFFFFFu);
        idx_final[tid] = n;
        out1[((size_t)b * LL + l0 + tid) * KK + k] = (float)n;
    }
    __syncthreads();

    // ---- Phase 4: cumulative output plane k = prev + cb[idx] (exact fp32) ----
    {
        const int ll = tid & 127;
        const int d0 = tid >> 7;
        const int nsel = idx_final[ll];
        const float* crow = cbk + (size_t)nsel * DD;
#pragma unroll
        for (int i = 0; i < 64; ++i) {
            int d = d0 * 64 + i;
            float p = (k > 0) ? prev[(size_t)d * LL + l0 + ll] : 0.f;
            cur[(size_t)d * LL + l0 + ll] = p + crow[d];
        }
    }
}

extern "C" void kernel_launch(void* const* d_in, const int* in_sizes, int n_in,
                              void* d_out, int out_size, void* d_ws, size_t ws_size,
                              hipStream_t stream) {
    const float* x  = (const float*)d_in[0];   // (B, D, L)
    const float* cb = (const float*)d_in[1];   // (K, N, D)
    float* out0 = (float*)d_out;                          // (B, K, D, L)
    float* out1 = out0 + (size_t)BB * KK * DD * LL;       // (B, L, K)

    // workspace: cnorm 32 KB | cbh 2 MB | cbm 2 MB  (4.25 MB total)
    float*    cnorm = (float*)d_ws;
    _Float16* cbh   = (_Float16*)((char*)d_ws + 32768);
    _Float16* cbm   = cbh + (size_t)KK * NN * DD;

    prep_kernel<<<(KK * NN * 16) / 256, 256, 0, stream>>>(cb, cnorm, cbh, cbm);
    for (int k = 0; k < KK; ++k) {
        rvq_step<<<BB * (LL / TL), 256, 0, stream>>>(
            x, cb + (size_t)k * NN * DD,
            cbh + (size_t)k * NN * DD, cbm + (size_t)k * NN * DD,
            cnorm + (size_t)k * NN, out0, out1, k);
    }
}

// Round 2
// 1046.600 us; speedup vs baseline: 2.8263x; 1.2591x over previous
//
#include <hip/hip_runtime.h>

// Residual VQ: B=16, D=128, L=4096, K=8 codebooks x N=1024 entries.
// out0 (B,K,D,L) cumulative quantization sums, out1 (B,L,K) argmin indices.
//
// R3 changes vs R2 (163 us/step, LDS-frag-bound 5:1, serial cb staging):
//  - x fragments register-resident (xf[2][4][4] half8 = 128 VGPR), loaded once
//    per block from LDS; x LDS freed -> codebook chunks DOUBLE-BUFFERED with
//    counted s_waitcnt vmcnt(16) + raw s_barrier (no vmcnt(0) drain in loop).
//  - A-frags shared across all 4 Dekker products: per t-step 16 ds_read_b128
//    feed 128 MFMAs (0.125 reads/MFMA, was 0.5). All products accumulate into
//    one acc (same score, reordered fp32 sum -- same noise class R2 passed with).
//  - TL=256: grid = 256 blocks = exactly 1/CU; waves own disjoint l-quarters
//    (no cross-wave argmin reduction); cb staging traffic halved.
//  - Phase 4 vectorized: float4 row gathers + float4 coalesced prev/cur via
//    4x4 register transpose.

#define BB 16
#define DD 128
#define LL 4096
#define KK 8
#define NN 1024

constexpr int TL  = 256;       // l-positions per block
constexpr int TN  = 128;       // n per chunk
constexpr int NCH = NN / TN;   // 8 chunks

typedef _Float16 half8 __attribute__((ext_vector_type(8)));
typedef float    f32x4 __attribute__((ext_vector_type(4)));

typedef __attribute__((address_space(3))) char lds_char;
typedef __attribute__((address_space(1))) const char gbl_char;

__device__ __forceinline__ void gload16(const void* g, void* l) {
    // stages 64 lanes x 16 B: per-lane global src, wave-uniform LDS base (+lane*16)
    __builtin_amdgcn_global_load_lds((gbl_char*)g, (lds_char*)l, 16, 0, 0);
}

// ---- prep: per codebook row: cnorm (fp32) + fp16 h/m split planes, pre-swizzled ----
__global__ void prep_kernel(const float* __restrict__ cb, float* __restrict__ cnorm,
                            _Float16* __restrict__ cbh, _Float16* __restrict__ cbm) {
    int t   = blockIdx.x * blockDim.x + threadIdx.x;   // 0 .. K*N*16-1
    int row = t >> 4;
    int g   = t & 15;
    const float* src = cb + (size_t)row * DD + g * 8;
    half8 h, m;
    float s = 0.f;
#pragma unroll
    for (int j = 0; j < 8; ++j) {
        float v = src[j];
        _Float16 hh = (_Float16)v;            // RN to fp16
        h[j] = hh;
        m[j] = (_Float16)(v - (float)hh);     // exact residual, RN to fp16
        s += v * v;
    }
    size_t pos = (size_t)row * DD + ((g ^ (row & 15)) * 8);
    *(half8*)(cbh + pos) = h;
    *(half8*)(cbm + pos) = m;
#pragma unroll
    for (int off = 1; off < 16; off <<= 1) s += __shfl_xor(s, off);
    if (g == 0) cnorm[row] = s;
}

__global__ __launch_bounds__(256, 1) void rvq_step(
    const float*    __restrict__ x,
    const float*    __restrict__ cbk,     // fp32 codebook k (N*D), for phase 4
    const _Float16* __restrict__ cbhk,    // pre-swizzled fp16 hi plane (N*D)
    const _Float16* __restrict__ cbmk,    // pre-swizzled fp16 mid plane (N*D)
    const float*    __restrict__ cnormk,  // N
    float* __restrict__ out0,             // B*K*D*L
    float* __restrict__ out1,             // B*L*K (float-encoded indices)
    int k)
{
    // 133 KB LDS -> 1 block/CU (by design; grid == 256 == CU count)
    // bufs: phase 1 holds x fp16 planes (buf0=hi, buf1=mid); after frag reads
    // they become the cb chunk double-buffer ({hi 32K | mid 32K} per buffer).
    __shared__ __align__(16) char bufs[2][65536];
    __shared__ __align__(16) float cnl[NN];     // all 1024 cnorms
    __shared__ int idx_final[TL];

    const int tid  = threadIdx.x;
    const int bidx = blockIdx.x;
    const int b    = bidx >> 4;             // LL/TL = 16 tiles per batch
    const int l0   = (bidx & 15) * TL;

    const float* prev = (k > 0) ? (out0 + ((size_t)b * KK + (k - 1)) * DD * LL) : nullptr;
    float* cur = out0 + ((size_t)b * KK + k) * DD * LL;

    const int lane = tid & 63;
    const int r15  = lane & 15;
    const int kg   = lane >> 4;     // 0..3 (k-group within MFMA)
    const int wid  = tid >> 6;      // 0..3: wave owns l-quarter [wid*64, wid*64+64)

    // ---- Phase 1: residual tile -> fp16 split planes in LDS (swizzled) ----
    {
        const int l  = tid;              // one l per thread
        const int sw = l & 15;
        const float* xb = x + (size_t)b * DD * LL + l0 + l;
        const float* pb = prev ? (prev + l0 + l) : nullptr;
#pragma unroll 2
        for (int g = 0; g < 16; ++g) {
            half8 ph, pm;
#pragma unroll
            for (int j = 0; j < 8; ++j) {
                int d = g * 8 + j;
                float v = xb[(size_t)d * LL];
                if (k > 0) v -= pb[(size_t)d * LL];
                _Float16 hh = (_Float16)v;
                ph[j] = hh;
                pm[j] = (_Float16)(v - (float)hh);
            }
            int off = l * 256 + ((g ^ sw) << 4);
            *(half8*)(bufs[0] + off) = ph;
            *(half8*)(bufs[1] + off) = pm;
        }
        // cnorm table (4 floats/thread)
        f32x4 cv = *(const f32x4*)(cnormk + tid * 4);
        *(f32x4*)(cnl + tid * 4) = cv;
    }
    __syncthreads();

    int offT[4];
#pragma unroll
    for (int t = 0; t < 4; ++t) offT[t] = (((t * 4 + kg) ^ r15) << 4);

    // ---- x fragments -> registers (invariant across all chunks) ----
    half8 xf[2][4][4];   // [plane][ni][t]  (static indexing only)
    {
        const int rbase = (wid * 64 + r15) * 256;
#pragma unroll
        for (int p = 0; p < 2; ++p)
#pragma unroll
            for (int ni = 0; ni < 4; ++ni)
#pragma unroll
                for (int t = 0; t < 4; ++t)
                    xf[p][ni][t] = *(const half8*)(bufs[p] + rbase + ni * 4096 + offT[t]);
    }
    __syncthreads();   // frag reads done before staging overwrites bufs

    float minv[4];
    int   minn[4];
#pragma unroll
    for (int i = 0; i < 4; ++i) { minv[i] = 3.4e38f; minn[i] = 0; }

    const int rowb = wid * 32;                       // wave's 32 rows of each chunk
    const char* gH = (const char*)cbhk + lane * 16;
    const char* gM = (const char*)cbmk + lane * 16;

    // 16 gload16 per wave per chunk (8 hi + 8 mid), pre-swizzled source, linear dest
#define STAGE(c) do { \
    const char* gh_ = gH + (size_t)((c) * TN + rowb) * 256; \
    const char* gm_ = gM + (size_t)((c) * TN + rowb) * 256; \
    char* lh_ = bufs[(c) & 1] + rowb * 256; \
    char* lm_ = bufs[(c) & 1] + 32768 + rowb * 256; \
    _Pragma("unroll") \
    for (int i_ = 0; i_ < 8; ++i_) { \
        gload16(gh_ + i_ * 1024, lh_ + i_ * 1024); \
        gload16(gm_ + i_ * 1024, lm_ + i_ * 1024); \
    } } while (0)

    STAGE(0);

    for (int c = 0; c < NCH; ++c) {
        if (c + 1 < NCH) {
            STAGE(c + 1);                                  // prefetch next chunk
            asm volatile("s_waitcnt vmcnt(16)" ::: "memory");  // chunk c landed, c+1 in flight
        } else {
            asm volatile("s_waitcnt vmcnt(0)" ::: "memory");
        }
        __builtin_amdgcn_s_barrier();                      // all waves' chunk-c loads done
        asm volatile("" ::: "memory");

        const char* bc = bufs[c & 1];
        f32x4 acc[8][4];
#pragma unroll
        for (int mi = 0; mi < 8; ++mi)
#pragma unroll
            for (int ni = 0; ni < 4; ++ni)
                acc[mi][ni] = (f32x4){0.f, 0.f, 0.f, 0.f};

        // 4 t-steps: 16 ds_read_b128 feed 128 MFMAs each (A-frags shared across
        // all 4 split products; all products accumulate into the same acc)
#pragma unroll
        for (int t = 0; t < 4; ++t) {
            half8 avh[8], avm[8];
#pragma unroll
            for (int mi = 0; mi < 8; ++mi)
                avh[mi] = *(const half8*)(bc + (mi * 16 + r15) * 256 + offT[t]);
#pragma unroll
            for (int mi = 0; mi < 8; ++mi)
                avm[mi] = *(const half8*)(bc + 32768 + (mi * 16 + r15) * 256 + offT[t]);
#pragma unroll
            for (int mi = 0; mi < 8; ++mi)
#pragma unroll
                for (int ni = 0; ni < 4; ++ni)
                    acc[mi][ni] = __builtin_amdgcn_mfma_f32_16x16x32_f16(
                        avh[mi], xf[0][ni][t], acc[mi][ni], 0, 0, 0);   // ch . xh
#pragma unroll
            for (int mi = 0; mi < 8; ++mi)
#pragma unroll
                for (int ni = 0; ni < 4; ++ni)
                    acc[mi][ni] = __builtin_amdgcn_mfma_f32_16x16x32_f16(
                        avm[mi], xf[0][ni][t], acc[mi][ni], 0, 0, 0);   // cm . xh
#pragma unroll
            for (int mi = 0; mi < 8; ++mi)
#pragma unroll
                for (int ni = 0; ni < 4; ++ni)
                    acc[mi][ni] = __builtin_amdgcn_mfma_f32_16x16x32_f16(
                        avh[mi], xf[1][ni][t], acc[mi][ni], 0, 0, 0);   // ch . xm
#pragma unroll
            for (int mi = 0; mi < 8; ++mi)
#pragma unroll
                for (int ni = 0; ni < 4; ++ni)
                    acc[mi][ni] = __builtin_amdgcn_mfma_f32_16x16x32_f16(
                        avm[mi], xf[1][ni][t], acc[mi][ni], 0, 0, 0);   // cm . xm
        }

        // ---- scores + running per-lane argmin ----
        // C/D layout: col = r15 (l), row = kg*4 + j (n within 16-tile)
        const int n0c = c * TN;
#pragma unroll
        for (int mi = 0; mi < 8; ++mi) {
            f32x4 cn = *(const f32x4*)(cnl + n0c + mi * 16 + kg * 4);
#pragma unroll
            for (int ni = 0; ni < 4; ++ni)
#pragma unroll
                for (int j = 0; j < 4; ++j) {
                    float sc = cn[j] - 2.f * acc[mi][ni][j];
                    // strict < + ascending per-lane visit order => earliest-n tie-break
                    if (sc < minv[ni]) { minv[ni] = sc; minn[ni] = n0c + mi * 16 + kg * 4 + j; }
                }
        }
        asm volatile("" ::: "memory");
        __builtin_amdgcn_s_barrier();   // all waves done reading bufs[c&1]
    }
#undef STAGE

    // ---- cross-kg argmin via packed keys; waves own disjoint l-quarters ----
    {
        unsigned long long key[4];
#pragma unroll
        for (int ni = 0; ni < 4; ++ni) {
            unsigned u = __float_as_uint(minv[ni]);
            u = (u & 0x80000000u) ? ~u : (u | 0x80000000u);   // monotone map
            key[ni] = ((unsigned long long)u << 32) | (unsigned)minn[ni];
        }
#pragma unroll
        for (int off = 16; off < 64; off <<= 1)
#pragma unroll
            for (int ni = 0; ni < 4; ++ni) {
                unsigned long long o = __shfl_xor(key[ni], off);
                if (o < key[ni]) key[ni] = o;
            }
        if (kg == 0) {
#pragma unroll
            for (int ni = 0; ni < 4; ++ni) {
                int n = (int)(key[ni] & 0xFFFFFFFFu);
                int l = wid * 64 + ni * 16 + r15;
                idx_final[l] = n;
                out1[((size_t)b * LL + l0 + l) * KK + k] = (float)n;
            }
        }
    }
    __syncthreads();

    // ---- Phase 4: cumulative plane k = prev + cb[idx] (exact fp32) ----
    // thread: 4 consecutive l (coalesced float4 prev/cur), 32 d; float4 row
    // gathers + 4x4 register transpose.
    {
        const int lq  = (tid & 63) * 4;
        const int dq0 = (tid >> 6) * 8;
        const f32x4* r0 = (const f32x4*)(cbk + (size_t)idx_final[lq + 0] * DD);
        const f32x4* r1 = (const f32x4*)(cbk + (size_t)idx_final[lq + 1] * DD);
        const f32x4* r2 = (const f32x4*)(cbk + (size_t)idx_final[lq + 2] * DD);
        const f32x4* r3 = (const f32x4*)(cbk + (size_t)idx_final[lq + 3] * DD);
        const size_t base = (size_t)l0 + lq;
#pragma unroll
        for (int dq = 0; dq < 8; ++dq) {
            int dqa = dq0 + dq;
            f32x4 c0 = r0[dqa], c1 = r1[dqa], c2 = r2[dqa], c3 = r3[dqa];
#pragma unroll
            for (int e = 0; e < 4; ++e) {
                int d = dqa * 4 + e;
                f32x4 pv = (k > 0) ? *(const f32x4*)(prev + (size_t)d * LL + base)
                                   : (f32x4){0.f, 0.f, 0.f, 0.f};
                f32x4 o = { pv[0] + c0[e], pv[1] + c1[e], pv[2] + c2[e], pv[3] + c3[e] };
                *(f32x4*)(cur + (size_t)d * LL + base) = o;
            }
        }
    }
}

extern "C" void kernel_launch(void* const* d_in, const int* in_sizes, int n_in,
                              void* d_out, int out_size, void* d_ws, size_t ws_size,
                              hipStream_t stream) {
    const float* x  = (const float*)d_in[0];   // (B, D, L)
    const float* cb = (const float*)d_in[1];   // (K, N, D)
    float* out0 = (float*)d_out;                          // (B, K, D, L)
    float* out1 = out0 + (size_t)BB * KK * DD * LL;       // (B, L, K)

    // workspace: cnorm 32 KB | cbh 2 MB | cbm 2 MB  (4.25 MB total)
    float*    cnorm = (float*)d_ws;
    _Float16* cbh   = (_Float16*)((char*)d_ws + 32768);
    _Float16* cbm   = cbh + (size_t)KK * NN * DD;

    prep_kernel<<<(KK * NN * 16) / 256, 256, 0, stream>>>(cb, cnorm, cbh, cbm);
    for (int k = 0; k < KK; ++k) {
        rvq_step<<<BB * (LL / TL), 256, 0, stream>>>(
            x, cb + (size_t)k * NN * DD,
            cbh + (size_t)k * NN * DD, cbm + (size_t)k * NN * DD,
            cnorm + (size_t)k * NN, out0, out1, k);
    }
}

// Round 3
// 751.183 us; speedup vs baseline: 3.9378x; 1.3933x over previous
//
#include <hip/hip_runtime.h>

// Residual VQ: B=16, D=128, L=4096, K=8 codebooks x N=1024 entries.
// out0 (B,K,D,L) cumulative quantization sums, out1 (B,L,K) argmin indices.
//
// R4 changes vs R3 (129 us/step; per-step x/prev re-read + re-split tax):
//  - ALL 8 k-steps fused into one persistent kernel (k-recurrence is l-local;
//    block owns its (b, l-tile) for all codebooks). 1 block/CU, grid=256.
//  - Residual lives IN the xf register fragments: per k, update
//    res = (f32)xh + (f32)xm - crow, re-split (error ~2^-22, same class as
//    the validated Dekker noise). out0 stays exact: prev-plane (own tile,
//    L2/L3-resident) + exact fp32 codebook rows.
//  - Staging flat-chunked across k (64 chunks) with counted vmcnt(16);
//    next codebook's chunk 0 prefetches under the per-k epilogue. Never
//    drains to 0 until the very last chunk.
//  - One-time prologue: direct global->register Dekker split (each dword
//    load instr = 4 fully-used 64B segments); no LDS phase-1 at all.
//  - Epilogue: butterfly argmin leaves each lane its own l's index ->
//    wave-local residual update; coalesced f32x4 cum pass via idxs LDS.

#define BB 16
#define DD 128
#define LL 4096
#define KK 8
#define NN 1024

constexpr int TL   = 256;            // l-positions per block
constexpr int TN   = 128;            // n per chunk
constexpr int NCHT = (KK * NN) / TN; // 64 flat chunks across all codebooks

typedef _Float16 half8 __attribute__((ext_vector_type(8)));
typedef float    f32x4 __attribute__((ext_vector_type(4)));

typedef __attribute__((address_space(3))) char lds_char;
typedef __attribute__((address_space(1))) const char gbl_char;

__device__ __forceinline__ void gload16(const void* g, void* l) {
    // stages 64 lanes x 16 B: per-lane global src, wave-uniform LDS base (+lane*16)
    __builtin_amdgcn_global_load_lds((gbl_char*)g, (lds_char*)l, 16, 0, 0);
}

// ---- prep: per codebook row: cnorm (fp32) + fp16 h/m split planes, pre-swizzled ----
__global__ void prep_kernel(const float* __restrict__ cb, float* __restrict__ cnorm,
                            _Float16* __restrict__ cbh, _Float16* __restrict__ cbm) {
    int t   = blockIdx.x * blockDim.x + threadIdx.x;   // 0 .. K*N*16-1
    int row = t >> 4;
    int g   = t & 15;
    const float* src = cb + (size_t)row * DD + g * 8;
    half8 h, m;
    float s = 0.f;
#pragma unroll
    for (int j = 0; j < 8; ++j) {
        float v = src[j];
        _Float16 hh = (_Float16)v;            // RN to fp16
        h[j] = hh;
        m[j] = (_Float16)(v - (float)hh);     // exact residual, RN to fp16
        s += v * v;
    }
    size_t pos = (size_t)row * DD + ((g ^ (row & 15)) * 8);
    *(half8*)(cbh + pos) = h;
    *(half8*)(cbm + pos) = m;
#pragma unroll
    for (int off = 1; off < 16; off <<= 1) s += __shfl_xor(s, off);
    if (g == 0) cnorm[row] = s;
}

__global__ __launch_bounds__(256, 1) void rvq_fused(
    const float*    __restrict__ x,     // (B, D, L)
    const float*    __restrict__ cbf,   // fp32 codebooks (K, N, D)
    const _Float16* __restrict__ cbh,   // pre-swizzled fp16 hi planes (K*N*D)
    const _Float16* __restrict__ cbm,   // pre-swizzled fp16 mid planes
    const float*    __restrict__ cnA,   // K*N cnorms
    float* __restrict__ out0,           // B*K*D*L
    float* __restrict__ out1)           // B*L*K (float-encoded indices)
{
    __shared__ __align__(16) char bufs[2][65536];   // cb chunk double-buffer
    __shared__ __align__(16) float cnl[NN];         // current codebook's cnorms
    __shared__ int idxs[TL];

    const int tid  = threadIdx.x;
    const int b    = blockIdx.x >> 4;            // LL/TL = 16 tiles per batch
    const int l0   = (blockIdx.x & 15) * TL;
    const int lane = tid & 63;
    const int r15  = lane & 15;
    const int kg   = lane >> 4;      // 0..3 (k-group within MFMA)
    const int wid  = tid >> 6;       // wave owns l-quarter [wid*64, wid*64+64)
    const int rowb = wid * 32;       // wave's 32 rows of each staged chunk

    // ---- prologue: x -> register fragments, Dekker split in regs (once) ----
    half8 xf0[4][4], xf1[4][4];      // [ni][t]: hi/mid planes of wave's tile
#pragma unroll
    for (int ni = 0; ni < 4; ++ni) {
        const float* xb = x + (size_t)b * DD * LL + l0 + wid * 64 + ni * 16 + r15;
#pragma unroll
        for (int t = 0; t < 4; ++t) {
            const int d0 = (t * 4 + kg) * 8;
            half8 h, m;
#pragma unroll
            for (int j = 0; j < 8; ++j) {
                float v = xb[(size_t)(d0 + j) * LL];
                _Float16 hh = (_Float16)v;
                h[j] = hh;
                m[j] = (_Float16)(v - (float)hh);
            }
            xf0[ni][t] = h;
            xf1[ni][t] = m;
        }
    }

    const char* gH = (const char*)cbh + rowb * 256 + lane * 16;
    const char* gM = (const char*)cbm + rowb * 256 + lane * 16;

#define STAGE(qq) do { \
    const char* gh_ = gH + (size_t)(qq) * 32768; \
    const char* gm_ = gM + (size_t)(qq) * 32768; \
    char* lh_ = bufs[(qq) & 1] + rowb * 256; \
    char* lm_ = bufs[(qq) & 1] + 32768 + rowb * 256; \
    _Pragma("unroll") \
    for (int i_ = 0; i_ < 8; ++i_) { \
        gload16(gh_ + i_ * 1024, lh_ + i_ * 1024); \
        gload16(gm_ + i_ * 1024, lm_ + i_ * 1024); \
    } } while (0)

    STAGE(0);

    int offT[4];
#pragma unroll
    for (int t = 0; t < 4; ++t) offT[t] = (((t * 4 + kg) ^ r15) << 4);
    const int rbA = r15 * 256;

    int q = 0;   // flat chunk counter (k*8 + c)
    for (int k = 0; k < KK; ++k) {
        const float* cbK  = cbf + (size_t)k * NN * DD;
        const float* prev = (k > 0) ? out0 + ((size_t)b * KK + (k - 1)) * DD * LL : nullptr;
        float*       cur  = out0 + ((size_t)b * KK + k) * DD * LL;

        // this k's cnorm table (race-free: prior k's readers are past chunk7's
        // closing barrier; visibility via chunk0's lgkmcnt(0)+barrier below)
        *(f32x4*)(cnl + tid * 4) = *(const f32x4*)(cnA + (size_t)k * NN + tid * 4);

        float minv[4];
        int   minn[4];
#pragma unroll
        for (int i = 0; i < 4; ++i) { minv[i] = 3.4e38f; minn[i] = 0; }

        for (int c = 0; c < 8; ++c, ++q) {
            if (q + 1 < NCHT) {
                STAGE(q + 1);                                   // prefetch (crosses k!)
                asm volatile("s_waitcnt vmcnt(16) lgkmcnt(0)" ::: "memory");
            } else {
                asm volatile("s_waitcnt vmcnt(0) lgkmcnt(0)" ::: "memory");
            }
            __builtin_amdgcn_s_barrier();
            asm volatile("" ::: "memory");

            const char* bc = bufs[q & 1];
            f32x4 acc[8][4];
#pragma unroll
            for (int mi = 0; mi < 8; ++mi)
#pragma unroll
                for (int ni = 0; ni < 4; ++ni)
                    acc[mi][ni] = (f32x4){0.f, 0.f, 0.f, 0.f};

            // 4 t-steps: 16 ds_read_b128 feed 128 MFMAs each
#pragma unroll
            for (int t = 0; t < 4; ++t) {
                half8 avh[8], avm[8];
#pragma unroll
                for (int mi = 0; mi < 8; ++mi)
                    avh[mi] = *(const half8*)(bc + mi * 4096 + rbA + offT[t]);
#pragma unroll
                for (int mi = 0; mi < 8; ++mi)
                    avm[mi] = *(const half8*)(bc + 32768 + mi * 4096 + rbA + offT[t]);
#pragma unroll
                for (int mi = 0; mi < 8; ++mi)
#pragma unroll
                    for (int ni = 0; ni < 4; ++ni)
                        acc[mi][ni] = __builtin_amdgcn_mfma_f32_16x16x32_f16(
                            avh[mi], xf0[ni][t], acc[mi][ni], 0, 0, 0);   // ch.xh
#pragma unroll
                for (int mi = 0; mi < 8; ++mi)
#pragma unroll
                    for (int ni = 0; ni < 4; ++ni)
                        acc[mi][ni] = __builtin_amdgcn_mfma_f32_16x16x32_f16(
                            avm[mi], xf0[ni][t], acc[mi][ni], 0, 0, 0);   // cm.xh
#pragma unroll
                for (int mi = 0; mi < 8; ++mi)
#pragma unroll
                    for (int ni = 0; ni < 4; ++ni)
                        acc[mi][ni] = __builtin_amdgcn_mfma_f32_16x16x32_f16(
                            avh[mi], xf1[ni][t], acc[mi][ni], 0, 0, 0);   // ch.xm
#pragma unroll
                for (int mi = 0; mi < 8; ++mi)
#pragma unroll
                    for (int ni = 0; ni < 4; ++ni)
                        acc[mi][ni] = __builtin_amdgcn_mfma_f32_16x16x32_f16(
                            avm[mi], xf1[ni][t], acc[mi][ni], 0, 0, 0);   // cm.xm
            }

            // scores + running per-lane argmin.  C/D: col=r15 (l), row=kg*4+j (n)
            const int n0c = c * TN;
#pragma unroll
            for (int mi = 0; mi < 8; ++mi) {
                f32x4 cn = *(const f32x4*)(cnl + n0c + mi * 16 + kg * 4);
#pragma unroll
                for (int ni = 0; ni < 4; ++ni)
#pragma unroll
                    for (int j = 0; j < 4; ++j) {
                        float sc = cn[j] - 2.f * acc[mi][ni][j];
                        // strict < + ascending visit order => earliest-n tie-break
                        if (sc < minv[ni]) { minv[ni] = sc; minn[ni] = n0c + mi * 16 + kg * 4 + j; }
                    }
            }
            asm volatile("" ::: "memory");
            __builtin_amdgcn_s_barrier();   // all waves done reading bufs[q&1]
        }

        // ---- per-k epilogue (next k's chunk-0 staging is in flight) ----
        unsigned long long key[4];
#pragma unroll
        for (int ni = 0; ni < 4; ++ni) {
            unsigned u = __float_as_uint(minv[ni]);
            u = (u & 0x80000000u) ? ~u : (u | 0x80000000u);   // monotone map
            key[ni] = ((unsigned long long)u << 32) | (unsigned)minn[ni];
        }
#pragma unroll
        for (int off = 16; off < 64; off <<= 1)
#pragma unroll
            for (int ni = 0; ni < 4; ++ni) {
                unsigned long long o = __shfl_xor(key[ni], off);
                if (o < key[ni]) key[ni] = o;
            }
        // every lane now holds the argmin for its own 4 l's
        if (kg == 0) {
#pragma unroll
            for (int ni = 0; ni < 4; ++ni) {
                int n  = (int)(key[ni] & 0xFFFFFFFFu);
                int ll = wid * 64 + ni * 16 + r15;
                idxs[ll] = n;
                out1[((size_t)b * LL + l0 + ll) * KK + k] = (float)n;
            }
        }
        asm volatile("s_waitcnt lgkmcnt(0)" ::: "memory");
        __builtin_amdgcn_s_barrier();   // idxs visible; keeps vm prefetch in flight
        asm volatile("" ::: "memory");

        // coalesced cum pass: thread = 4 consecutive l x 32 d, f32x4 everywhere.
        // prev plane is this block's own tile written last k (L2/L3-resident).
        {
            const int lq  = (tid & 63) * 4;
            const int dq0 = (tid >> 6) * 8;
            const f32x4* r0 = (const f32x4*)(cbK + (size_t)idxs[lq + 0] * DD);
            const f32x4* r1 = (const f32x4*)(cbK + (size_t)idxs[lq + 1] * DD);
            const f32x4* r2 = (const f32x4*)(cbK + (size_t)idxs[lq + 2] * DD);
            const f32x4* r3 = (const f32x4*)(cbK + (size_t)idxs[lq + 3] * DD);
            const size_t base = (size_t)l0 + lq;
#pragma unroll
            for (int dq = 0; dq < 8; ++dq) {
                int dqa = dq0 + dq;
                f32x4 c0 = r0[dqa], c1 = r1[dqa], c2 = r2[dqa], c3 = r3[dqa];
#pragma unroll
                for (int e = 0; e < 4; ++e) {
                    int d = dqa * 4 + e;
                    f32x4 pv = (k > 0) ? *(const f32x4*)(prev + (size_t)d * LL + base)
                                       : (f32x4){0.f, 0.f, 0.f, 0.f};
                    f32x4 o = { pv[0] + c0[e], pv[1] + c1[e], pv[2] + c2[e], pv[3] + c3[e] };
                    *(f32x4*)(cur + (size_t)d * LL + base) = o;
                }
            }
        }

        // wave-local residual update in registers: res = (xh + xm) - crow, re-split
        if (k + 1 < KK) {
#pragma unroll
            for (int ni = 0; ni < 4; ++ni) {
                const float* cr = cbK + (size_t)(unsigned)(key[ni] & 0xFFFFFFFFu) * DD;
#pragma unroll
                for (int t = 0; t < 4; ++t) {
                    const int d0 = (t * 4 + kg) * 8;
                    f32x4 ca = *(const f32x4*)(cr + d0);
                    f32x4 cb4 = *(const f32x4*)(cr + d0 + 4);
                    half8 h = xf0[ni][t], m = xf1[ni][t];
#pragma unroll
                    for (int j = 0; j < 4; ++j) {
                        float r = (float)h[j] + (float)m[j] - ca[j];
                        _Float16 hh = (_Float16)r;
                        h[j] = hh;
                        m[j] = (_Float16)(r - (float)hh);
                    }
#pragma unroll
                    for (int j = 0; j < 4; ++j) {
                        float r = (float)h[j + 4] + (float)m[j + 4] - cb4[j];
                        _Float16 hh = (_Float16)r;
                        h[j + 4] = hh;
                        m[j + 4] = (_Float16)(r - (float)hh);
                    }
                    xf0[ni][t] = h;
                    xf1[ni][t] = m;
                }
            }
        }
        // no barrier needed: next k's chunk-0 vmcnt+barrier re-syncs
    }
#undef STAGE
}

extern "C" void kernel_launch(void* const* d_in, const int* in_sizes, int n_in,
                              void* d_out, int out_size, void* d_ws, size_t ws_size,
                              hipStream_t stream) {
    const float* x  = (const float*)d_in[0];   // (B, D, L)
    const float* cb = (const float*)d_in[1];   // (K, N, D)
    float* out0 = (float*)d_out;                          // (B, K, D, L)
    float* out1 = out0 + (size_t)BB * KK * DD * LL;       // (B, L, K)

    // workspace: cnorm 32 KB | cbh 2 MB | cbm 2 MB  (4.25 MB total)
    float*    cnorm = (float*)d_ws;
    _Float16* cbh   = (_Float16*)((char*)d_ws + 32768);
    _Float16* cbm   = cbh + (size_t)KK * NN * DD;

    prep_kernel<<<(KK * NN * 16) / 256, 256, 0, stream>>>(cb, cnorm, cbh, cbm);
    rvq_fused<<<BB * (LL / TL), 256, 0, stream>>>(x, cb, cbh, cbm, cnorm, out0, out1);
}